// Round 10
// baseline (966.450 us; speedup 1.0000x reference)
//
#include <hip/hip_runtime.h>

// CKAFormer R17 (from R16 = 907.5us best; R16 post-mortem: lb(256,4) matched
// prediction — upd1 62.5->52us, Occ 21->31.6%. upd1 still top (6x52=312us),
// nothing saturated (HBM 24/MFMA 29/VALU 30) -> epilogue+latency heavy.
// R17 = single change: upd1_k epilogue PAIR-ACCESS (the proven EPI0 pattern):
// - was: per thread 16 scattered 2B loads (Xm base) + 16 scattered 2B stores.
// - now: adjacent-n lane pairs via __shfl_xor(acc,1); even lanes do 4B dword
//   base-load + dword store (swz preserves bit0: n even -> so even, so+1 =
//   swz(n+1)). Halves scattered-access instruction count and partial-line
//   traffic. vf bit-identical (same FMA expr); only ssl f32 sum ORDER changes
//   — already nondeterministic across the 8 atomic partials per row.
// This is R14's goal done right: R14 removed the pacing loads but kept 2B
// scattered stores (WRITE tripled); R17 pairs BOTH sides like EPI0 has done
// at full speed since R8. Everything else byte-identical to R16.

#define N_ROWS 16384
#define DIM 1024
#define HID 16
#define OUTD 64
#define DEPTH 6
#define GAMMA 1e-4f

typedef short bf16x8 __attribute__((ext_vector_type(8)));
typedef unsigned short u16x8 __attribute__((ext_vector_type(8)));
typedef float f32x4 __attribute__((ext_vector_type(4)));

#define AS1C(p) ((const __attribute__((address_space(1))) void*)(p))
#define AS3(p)  ((__attribute__((address_space(3))) void*)(p))

__device__ __forceinline__ unsigned short f2bf(float f) {
    unsigned u = __builtin_bit_cast(unsigned, f);
    u += 0x7fffu + ((u >> 16) & 1u);   // round-to-nearest-even
    return (unsigned short)(u >> 16);
}
__device__ __forceinline__ float b2f(ushort u) {
    unsigned x = ((unsigned)u) << 16;
    return __builtin_bit_cast(float, x);
}
// stored offset of logical element n within a swizzled row keyed by (row&7)
__device__ __forceinline__ int swz(int n, int row) {
    return (n & ~63) | ((((n >> 3) & 7) ^ (row & 7)) << 3) | (n & 7);
}

// ---------------------------------------------------------------------------
// Once per launch: master Xm = bf16(X) swizzled rows + ssout[row] = ||X[row]||^2.
__global__ __launch_bounds__(256) void tobf16_k(const float* __restrict__ X,
        ushort* __restrict__ Xm, float* __restrict__ ssout) {
    int row = blockIdx.x, t = threadIdx.x;
    float4 v = ((const float4*)(X + (size_t)row * DIM))[t];
    ushort4 o4;
    o4.x = f2bf(v.x); o4.y = f2bf(v.y); o4.z = f2bf(v.z); o4.w = f2bf(v.w);
    *(ushort4*)(Xm + (size_t)row * DIM + swz(t * 4, row)) = o4;
    float ss = v.x * v.x + v.y * v.y + v.z * v.z + v.w * v.w;
    for (int o = 32; o > 0; o >>= 1) ss += __shfl_down(ss, o);
    __shared__ float wsum[4];
    if ((t & 63) == 0) wsum[t >> 6] = ss;
    __syncthreads();
    if (t == 0) ssout[row] = wsum[0] + wsum[1] + wsum[2] + wsum[3];
}

// ---------------------------------------------------------------------------
// XnT[d][k] = bf16(Xm[k][d] / ||X[k]||), swizzled by d. LDS 64x65 f32 tile.
__device__ __forceinline__ void transpose_body(const ushort* __restrict__ Xm,
        const float* __restrict__ ss, ushort* __restrict__ XnT,
        int bx, int by, float* ts, float* riS) {
    int r0 = bx * 64;   // source row (k) tile
    int c0 = by * 64;   // source col (d) tile
    int t = threadIdx.x;
    if (t < 64) riS[t] = 1.0f / sqrtf(ss[r0 + t]);
    __syncthreads();
#pragma unroll
    for (int i = 0; i < 2; ++i) {
        int idx = i * 256 + t;
        int r = idx >> 3, lg = idx & 7;
        int rr = r0 + r;
        const ushort* p = Xm + (size_t)rr * DIM + c0 + ((lg ^ (rr & 7)) << 3);
        u16x8 a = *(const u16x8*)p;
        float s = riS[r];
        float* d = &ts[r * 65 + lg * 8];
#pragma unroll
        for (int u = 0; u < 8; ++u) d[u] = b2f(a[u]) * s;
    }
    __syncthreads();
#pragma unroll
    for (int i = 0; i < 2; ++i) {
        int g = i * 256 + t;
        int c = g >> 3;
        int rg = g & 7;
        u16x8 pk;
#pragma unroll
        for (int u = 0; u < 8; ++u) pk[u] = f2bf(ts[(rg * 8 + u) * 65 + c]);
        *(u16x8*)(XnT + (size_t)(c0 + c) * N_ROWS + r0 + ((rg ^ (c & 7)) << 3)) = pk;
    }
}

// ---------------------------------------------------------------------------
// z[m][h] = (Xm[m]·W1[:,h]) / ||X[m]|| + b1[h]   (ss=nullptr -> no scale; final).
__device__ __forceinline__ void zgemm_body(const ushort* __restrict__ Xm,
        const ushort* __restrict__ W1T, const float* __restrict__ b1,
        float* __restrict__ z, const float* __restrict__ ss, int bidx) {
    int t = threadIdx.x;
    int wave = t >> 6, lane = t & 63;
    int rl = lane & 15, q = lane >> 4;
    int rowbase = bidx * 64 + wave * 16;
    int m = rowbase + rl;
    int msw = m & 7;
    const ushort* arow = Xm + (size_t)m * DIM;
    const ushort* brow = W1T + (size_t)rl * DIM + q * 8;
    f32x4 acc = {0.f, 0.f, 0.f, 0.f};
#pragma unroll 8
    for (int kt = 0; kt < DIM; kt += 32) {
        int gl = ((kt >> 3) & 7) | q;
        int off = (kt & ~63) + ((gl ^ msw) << 3);
        bf16x8 a = *(const bf16x8*)(arow + off);
        bf16x8 b = *(const bf16x8*)(brow + kt);
        acc = __builtin_amdgcn_mfma_f32_16x16x32_bf16(a, b, acc, 0, 0, 0);
    }
#pragma unroll
    for (int rg = 0; rg < 4; ++rg) {
        int mm = rowbase + q * 4 + rg;
        float s = ss ? 1.0f / sqrtf(ss[mm]) : 1.0f;
        z[(size_t)mm * HID + rl] = acc[rg] * s + b1[rl];
    }
}

// ---------------------------------------------------------------------------
// Fused transpose (blocks 0..4095) + zgemm (blocks 4096..4351).
__global__ __launch_bounds__(256) void txz_k(const ushort* __restrict__ Xm,
        const float* __restrict__ ss, ushort* __restrict__ XnT,
        const ushort* __restrict__ W1T, const float* __restrict__ b1,
        float* __restrict__ z) {
    __shared__ float ts[64 * 65];
    __shared__ float riS[64];
    int bid = blockIdx.x;
    if (bid < 4096) transpose_body(Xm, ss, XnT, bid & 255, bid >> 8, ts, riS);
    else            zgemm_body(Xm, W1T, b1, z, ss, bid - 4096);
}

// standalone wrappers (small path / final)
__global__ __launch_bounds__(256) void transpose_k(const ushort* __restrict__ Xm,
        const float* __restrict__ ss, ushort* __restrict__ XnT) {
    __shared__ float ts[64 * 65];
    __shared__ float riS[64];
    transpose_body(Xm, ss, XnT, blockIdx.x, blockIdx.y, ts, riS);
}
__global__ __launch_bounds__(256) void zgemm_k(const ushort* __restrict__ Xm,
        const ushort* __restrict__ W1T, const float* __restrict__ b1,
        float* __restrict__ z, const float* __restrict__ ss) {
    zgemm_body(Xm, W1T, b1, z, ss, blockIdx.x);
}

// ---------------------------------------------------------------------------
__global__ __launch_bounds__(256) void prep_w1t_k(const float* __restrict__ W1,
        ushort* __restrict__ W1T) {
    int idx = blockIdx.x * 256 + threadIdx.x;   // 16384
    int h = idx >> 10, j = idx & 1023;
    W1T[idx] = f2bf(W1[j * HID + h]);
}

// ---------------------------------------------------------------------------
// Per row: h = relu(z); logits = h@W2 + b2; softmax -> Pb (swizzled by m&7)
// + PTb (rows o, swizzled by o&7), or (do_softmax=0) logits f32 to out.
__global__ __launch_bounds__(256) void head_k(const float* __restrict__ z,
        const float* __restrict__ W2, const float* __restrict__ b2,
        ushort* __restrict__ Pb, ushort* __restrict__ PTb,
        float* __restrict__ out, int do_softmax) {
    __shared__ float w2s[HID * OUTD];
    __shared__ float b2s[OUTD];
    int t = threadIdx.x;
    ((float4*)w2s)[t] = ((const float4*)W2)[t];
    if (t < OUTD) b2s[t] = b2[t];
    __syncthreads();
    int m = blockIdx.x * 256 + t;
    float h[HID];
    const float4* zp = (const float4*)(z + (size_t)m * HID);
#pragma unroll
    for (int i = 0; i < 4; ++i) {
        float4 v = zp[i];
        h[i * 4 + 0] = fmaxf(v.x, 0.f); h[i * 4 + 1] = fmaxf(v.y, 0.f);
        h[i * 4 + 2] = fmaxf(v.z, 0.f); h[i * 4 + 3] = fmaxf(v.w, 0.f);
    }
    float lo[OUTD];
#pragma unroll
    for (int o = 0; o < OUTD; ++o) lo[o] = b2s[o];
    for (int i = 0; i < HID; ++i) {
        float hv = h[i];
#pragma unroll
        for (int o = 0; o < OUTD; ++o) lo[o] += hv * w2s[i * OUTD + o];
    }
    if (do_softmax) {
        float mx = lo[0];
#pragma unroll
        for (int o = 1; o < OUTD; ++o) mx = fmaxf(mx, lo[o]);
        float sm = 0.f;
#pragma unroll
        for (int o = 0; o < OUTD; ++o) { float e = __expf(lo[o] - mx); lo[o] = e; sm += e; }
        float inv = 1.0f / sm;
#pragma unroll
        for (int o8 = 0; o8 < 8; ++o8) {
            u16x8 pk;
#pragma unroll
            for (int u = 0; u < 8; ++u) pk[u] = f2bf(lo[o8 * 8 + u] * inv);
            ((u16x8*)(Pb + (size_t)m * OUTD))[o8 ^ (m & 7)] = pk;
        }
#pragma unroll
        for (int o = 0; o < OUTD; ++o)
            PTb[(size_t)o * N_ROWS + swz(m, o)] = f2bf(lo[o] * inv);
    } else {
        float4* op = (float4*)(out + (size_t)m * OUTD);
#pragma unroll
        for (int o4 = 0; o4 < 16; ++o4) {
            float4 v; v.x = lo[o4 * 4 + 0]; v.y = lo[o4 * 4 + 1];
            v.z = lo[o4 * 4 + 2]; v.w = lo[o4 * 4 + 3];
            op[o4] = v;
        }
    }
}

// ---------------------------------------------------------------------------
// Pass A: coalesced split-K reduction -> compact bf16 sums.
__global__ __launch_bounds__(256) void reduce_k(const ushort* __restrict__ Gp,
        const ushort* __restrict__ PXp, ushort* __restrict__ Gsum,
        ushort* __restrict__ PXsum, int nzg, int nzp) {
    int idx = blockIdx.x * 256 + threadIdx.x;   // 81920 units of 8 elems
    if (idx < 73728) {
        size_t off = (size_t)idx * 8;
        float acc[8] = {0.f, 0.f, 0.f, 0.f, 0.f, 0.f, 0.f, 0.f};
        for (int zz = 0; zz < nzg; ++zz) {
            u16x8 v = *(const u16x8*)(Gp + (size_t)zz * 589824 + off);
#pragma unroll
            for (int u = 0; u < 8; ++u) acc[u] += b2f(v[u]);
        }
        u16x8 o;
#pragma unroll
        for (int u = 0; u < 8; ++u) o[u] = f2bf(acc[u]);
        *(u16x8*)(Gsum + off) = o;
    } else {
        size_t off = (size_t)(idx - 73728) * 8;
        float acc[8] = {0.f, 0.f, 0.f, 0.f, 0.f, 0.f, 0.f, 0.f};
        for (int zz = 0; zz < nzp; ++zz) {
            u16x8 v = *(const u16x8*)(PXp + (size_t)zz * 65536 + off);
#pragma unroll
            for (int u = 0; u < 8; ++u) acc[u] += b2f(v[u]);
        }
        u16x8 o;
#pragma unroll
        for (int u = 0; u < 8; ++u) o[u] = f2bf(acc[u]);
        *(u16x8*)(PXsum + off) = o;
    }
}

// ---------------------------------------------------------------------------
// Pass B: gather/mirror/swizzle of the L2-resident sums + zero next ssacc.
__global__ __launch_bounds__(256) void castgp_k(const ushort* __restrict__ Gsum,
        const ushort* __restrict__ PXsum, ushort* __restrict__ Gb,
        ushort* __restrict__ PtXTb, float* __restrict__ ssz) {
    if (blockIdx.x < 64) ssz[blockIdx.x * 256 + threadIdx.x] = 0.f;
    int idx = blockIdx.x * 256 + threadIdx.x;   // 278528 units
    if (idx < 262144) {
        int n = idx >> 8;
        int so = (idx & 255) * 4;
        int k0 = (so & ~63) | ((((so >> 3) & 7) ^ (n & 7)) << 3) | (so & 7);
        ushort po[4];
#pragma unroll
        for (int u = 0; u < 4; ++u) {
            int kk = k0 + u;
            int a = min(n, kk), b = max(n, kk);
            int tm = a >> 7, tn = b >> 7;
            int tlin = tm * 8 - ((tm * (tm - 1)) >> 1) + (tn - tm);
            size_t off = (size_t)tlin * 16384 + (size_t)(a & 127) * 128 + (b & 127);
            po[u] = (ushort)(Gsum[off] ^ 0x8000u);   // negate via sign bit
        }
        ushort4 o; o.x = po[0]; o.y = po[1]; o.z = po[2]; o.w = po[3];
        *(ushort4*)(Gb + (size_t)n * DIM + so) = o;
    } else {
        int vv = idx - 262144;                  // 16384 units
        int d = vv >> 4;
        int so = (vv & 15) * 4;
        int k0 = ((((so >> 3) & 7) ^ (d & 7)) << 3) | (so & 7);
        const ushort* src = PXsum + (size_t)d * OUTD + k0;
        ushort4 o; o.x = src[0]; o.y = src[1]; o.z = src[2]; o.w = src[3];
        *(ushort4*)(PtXTb + (size_t)d * OUTD + so) = o;
    }
}

// ---------------------------------------------------------------------------
// Partial-store NT MFMA GEMM body (R5-proven loop; EPI0 only).
template<int BM, int BN, int TRI>
__device__ __forceinline__ void gemm0_body(
        const ushort* __restrict__ A0, int lda0,
        const ushort* __restrict__ B0, int ldb0, int k0len,
        ushort* __restrict__ C, int pstride, int nz,
        int bx, int by, int bz, ushort* ls) {
    constexpr int WTN = BN / 2;
    constexpr int NF = WTN / 16;
    constexpr int NAW = BM / 64;     // waves staging A
    constexpr int NBW = BN / 64;     // waves staging B
    ushort* lsA = ls;
    ushort* lsB = ls + BM * 64;
    int t = threadIdx.x;
    int wave = t >> 6, lane = t & 63;
    int rl = lane & 15, q = lane >> 4;
    int wm = wave & 1, wn = wave >> 1;
    int m0, n0, zidx, tlin = 0;
    if (TRI) {
        int bid = bx;
        int bxx, tm = 0;
        if (nz == 16) {                 // R7-proven mapping: grid 8*36*2
            int rest = bid >> 3;
            bxx = rest % 36;
            int zhi = rest / 36;
            zidx = (bid & 7) | (zhi << 3);
        } else {                        // fallback: grid 36*4
            zidx = bid & 3;
            bxx = bid >> 2;
        }
        tlin = bxx;
        while (bxx >= 8 - tm) { bxx -= 8 - tm; ++tm; }
        m0 = tm * 128; n0 = (tm + bxx) * 128;
    } else {
        m0 = bx * BM; n0 = by * BN; zidx = bz;
    }
    int lrow8 = lane >> 3, lgrp = lane & 7;
    bool isA = wave < NAW;
    bool active = wave < NAW + NBW;
    int wlocal = isA ? wave : wave - NAW;
    ushort* dstb = ls + (isA ? 0 : BM * 64) + wlocal * 4096;

    f32x4 acc[4][NF];
#pragma unroll
    for (int i = 0; i < 4; ++i)
#pragma unroll
        for (int j = 0; j < NF; ++j) acc[i][j] = f32x4{0.f, 0.f, 0.f, 0.f};

    const ushort* srcb;
    size_t ldS;
    if (isA) {
        srcb = A0 + (size_t)(m0 + wlocal * 64 + lrow8) * lda0 + lgrp * 8;
        ldS = (size_t)lda0;
    } else {
        srcb = B0 + (size_t)(n0 + wlocal * 64 + lrow8) * ldb0 + lgrp * 8;
        ldS = (size_t)ldb0;
    }
    srcb += zidx * k0len;
    for (int kt = 0; kt < k0len; kt += 64) {
        if (active) {
#pragma unroll
            for (int c = 0; c < 8; ++c)
                __builtin_amdgcn_global_load_lds(AS1C(srcb + c * 8 * ldS),
                                                 AS3(dstb + c * 512), 16, 0, 0);
            srcb += 64;
        }
        __syncthreads();
#pragma unroll
        for (int s = 0; s < 2; ++s) {
            bf16x8 af[4], bfr[NF];
#pragma unroll
            for (int i = 0; i < 4; ++i) {
                int row = wm * 64 + i * 16 + rl;
                int sg = ((s << 2) | q) ^ (row & 7);
                af[i] = *(const bf16x8*)&lsA[row * 64 + sg * 8];
            }
#pragma unroll
            for (int j = 0; j < NF; ++j) {
                int row = wn * WTN + j * 16 + rl;
                int sg = ((s << 2) | q) ^ (row & 7);
                bfr[j] = *(const bf16x8*)&lsB[row * 64 + sg * 8];
            }
#pragma unroll
            for (int i = 0; i < 4; ++i)
#pragma unroll
                for (int j = 0; j < NF; ++j)
                    acc[i][j] = __builtin_amdgcn_mfma_f32_16x16x32_bf16(
                        af[i], bfr[j], acc[i][j], 0, 0, 0);
        }
        __syncthreads();
    }

    // plain bf16 pair stores into this z-slice's partial buffer
    ushort* Cb = C + (size_t)zidx * (size_t)pstride;
#pragma unroll
    for (int i = 0; i < 4; ++i)
#pragma unroll
        for (int j = 0; j < NF; ++j)
#pragma unroll
            for (int rg = 0; rg < 4; ++rg) {
                float v = acc[i][j][rg];
                float vp = __shfl_xor(v, 1);   // partner lane's (n^1) value
                if ((rl & 1) == 0) {
                    int ml = wm * 64 + i * 16 + q * 4 + rg;
                    int nl = wn * WTN + j * 16 + rl;
                    size_t off;
                    if (TRI)
                        off = (size_t)tlin * (BM * BN) + (size_t)ml * BN + nl;
                    else
                        off = (size_t)(m0 + ml) * 0 + (size_t)(m0 + ml) * OUTD + nl; // non-TRI: ldc=OUTD
                    unsigned pk = (unsigned)f2bf(v) | ((unsigned)f2bf(vp) << 16);
                    *(unsigned*)(Cb + off) = pk;
                }
            }
}

template<int BM, int BN, int TRI>
__global__ __launch_bounds__(256, 4) void gemm_nt_k(
        const ushort* __restrict__ A0, int lda0,
        const ushort* __restrict__ B0, int ldb0, int k0len,
        ushort* __restrict__ C, int pstride, int nz) {
    __shared__ ushort ls[(BM + BN) * 64];
    gemm0_body<BM, BN, TRI>(A0, lda0, B0, ldb0, k0len, C, pstride, nz,
        blockIdx.x, blockIdx.y, blockIdx.z, ls);
}

// ---------------------------------------------------------------------------
// Fused G-gemm (blocks 0..575, TRI split-K 16) + PtX-gemm (576..831, split-K 32).
__global__ __launch_bounds__(256, 4) void gp_k(const ushort* __restrict__ XnT,
        const ushort* __restrict__ PTb, ushort* __restrict__ Gpart,
        ushort* __restrict__ PXpart) {
    __shared__ ushort ls[256 * 64];
    int bid = blockIdx.x;
    if (bid < 576) {
        gemm0_body<128, 128, 1>(XnT, N_ROWS, XnT, N_ROWS, 1024,
            Gpart, 36 * 16384, 16, bid, 0, 0, ls);
    } else {
        int b2 = bid - 576;
        gemm0_body<128, 64, 0>(XnT, N_ROWS, PTb, N_ROWS, 512,
            PXpart, DIM * OUTD, 0, b2 & 7, 0, b2 >> 3, ls);
    }
}

// ---------------------------------------------------------------------------
// Dedicated update gemm: X_{t+1} = Xn + g*(P@PtX - Xn@G).
// seg0: Xm(ld DIM) @ Gb(ld DIM)^T, K=1024. rvv scale. seg1: Pb @ PtXTb
// (ld OUTD), K=64. Epilogue (R17): adjacent-n lane-paired dword base-load +
// dword store (EPI0 pattern); vf bit-identical to R16.
__global__ __launch_bounds__(256, 4) void upd1_k(
        const ushort* __restrict__ Xm, const ushort* __restrict__ Gb,
        const ushort* __restrict__ Pb, const ushort* __restrict__ PtXTb,
        ushort* __restrict__ Cm, const float* __restrict__ ssrd,
        float gamma, float* __restrict__ ssacc) {
    __shared__ ushort ls[256 * 64];
    ushort* lsA = ls;
    ushort* lsB = ls + 128 * 64;
    int t = threadIdx.x;
    int wave = t >> 6, lane = t & 63;
    int rl = lane & 15, q = lane >> 4;
    int wm = wave & 1, wn = wave >> 1;
    int m0 = blockIdx.x * 128, n0 = blockIdx.y * 128;
    int lrow8 = lane >> 3, lgrp = lane & 7;
    bool isA = wave < 2;
    int wlocal = isA ? wave : wave - 2;
    ushort* dstb = ls + (isA ? 0 : 8192) + wlocal * 4096;

    f32x4 acc[4][4];
#pragma unroll
    for (int i = 0; i < 4; ++i)
#pragma unroll
        for (int j = 0; j < 4; ++j) acc[i][j] = f32x4{0.f, 0.f, 0.f, 0.f};

    // seg0: K=1024
    {
        const ushort* srcb = isA
            ? Xm + (size_t)(m0 + wlocal * 64 + lrow8) * DIM + lgrp * 8
            : Gb + (size_t)(n0 + wlocal * 64 + lrow8) * DIM + lgrp * 8;
        for (int kt = 0; kt < 1024; kt += 64) {
#pragma unroll
            for (int c = 0; c < 8; ++c)
                __builtin_amdgcn_global_load_lds(AS1C(srcb + c * 8 * DIM),
                                                 AS3(dstb + c * 512), 16, 0, 0);
            srcb += 64;
            __syncthreads();
#pragma unroll
            for (int s = 0; s < 2; ++s) {
                bf16x8 af[4], bfr[4];
#pragma unroll
                for (int i = 0; i < 4; ++i) {
                    int row = wm * 64 + i * 16 + rl;
                    int sg = ((s << 2) | q) ^ (row & 7);
                    af[i] = *(const bf16x8*)&lsA[row * 64 + sg * 8];
                }
#pragma unroll
                for (int j = 0; j < 4; ++j) {
                    int row = wn * 64 + j * 16 + rl;
                    int sg = ((s << 2) | q) ^ (row & 7);
                    bfr[j] = *(const bf16x8*)&lsB[row * 64 + sg * 8];
                }
#pragma unroll
                for (int i = 0; i < 4; ++i)
#pragma unroll
                    for (int j = 0; j < 4; ++j)
                        acc[i][j] = __builtin_amdgcn_mfma_f32_16x16x32_bf16(
                            af[i], bfr[j], acc[i][j], 0, 0, 0);
            }
            __syncthreads();
        }
    }

    // rvv scale (Xn@G needs rinv[m])
    float rvv[4][4];
#pragma unroll
    for (int i = 0; i < 4; ++i)
#pragma unroll
        for (int rg = 0; rg < 4; ++rg) {
            rvv[i][rg] = 1.0f / sqrtf(ssrd[m0 + wm * 64 + i * 16 + q * 4 + rg]);
#pragma unroll
            for (int j = 0; j < 4; ++j) acc[i][j][rg] *= rvv[i][rg];
        }

    // seg1: K=64
    {
        const ushort* srcb = isA
            ? Pb + (size_t)(m0 + wlocal * 64 + lrow8) * OUTD + lgrp * 8
            : PtXTb + (size_t)(n0 + wlocal * 64 + lrow8) * OUTD + lgrp * 8;
#pragma unroll
        for (int c = 0; c < 8; ++c)
            __builtin_amdgcn_global_load_lds(AS1C(srcb + c * 8 * OUTD),
                                             AS3(dstb + c * 512), 16, 0, 0);
        __syncthreads();
#pragma unroll
        for (int s = 0; s < 2; ++s) {
            bf16x8 af[4], bfr[4];
#pragma unroll
            for (int i = 0; i < 4; ++i) {
                int row = wm * 64 + i * 16 + rl;
                int sg = ((s << 2) | q) ^ (row & 7);
                af[i] = *(const bf16x8*)&lsA[row * 64 + sg * 8];
            }
#pragma unroll
            for (int j = 0; j < 4; ++j) {
                int row = wn * 64 + j * 16 + rl;
                int sg = ((s << 2) | q) ^ (row & 7);
                bfr[j] = *(const bf16x8*)&lsB[row * 64 + sg * 8];
            }
#pragma unroll
            for (int i = 0; i < 4; ++i)
#pragma unroll
                for (int j = 0; j < 4; ++j)
                    acc[i][j] = __builtin_amdgcn_mfma_f32_16x16x32_bf16(
                        af[i], bfr[j], acc[i][j], 0, 0, 0);
        }
    }

    // epilogue (R17): adjacent-n lane pairs; even rl does dword base-load +
    // dword store for (n, n+1). swz preserves bit0 (n even -> so even,
    // swz(n+1,m) = so+1). vf formula identical to R16; ssl gathers both
    // pair members on the even lane (odd lanes contribute 0; xor-tree sums).
#pragma unroll
    for (int i = 0; i < 4; ++i)
#pragma unroll
        for (int rg = 0; rg < 4; ++rg) {
            int m = m0 + wm * 64 + i * 16 + q * 4 + rg;
            float ssl = 0.f;
#pragma unroll
            for (int j = 0; j < 4; ++j) {
                int n = n0 + wn * 64 + j * 16 + rl;
                float v = acc[i][j][rg];
                float vp = __shfl_xor(v, 1);   // partner lane's (n^1) value
                if ((rl & 1) == 0) {
                    int so = swz(n, m);
                    unsigned bp = *(const unsigned*)&Xm[(size_t)m * DIM + so];
                    float vf0 = b2f((ushort)(bp & 0xffffu)) * rvv[i][rg] + gamma * v;
                    float vf1 = b2f((ushort)(bp >> 16)) * rvv[i][rg] + gamma * vp;
                    *(unsigned*)&Cm[(size_t)m * DIM + so] =
                        (unsigned)f2bf(vf0) | ((unsigned)f2bf(vf1) << 16);
                    ssl += vf0 * vf0 + vf1 * vf1;
                }
            }
            ssl += __shfl_xor(ssl, 1);
            ssl += __shfl_xor(ssl, 2);
            ssl += __shfl_xor(ssl, 4);
            ssl += __shfl_xor(ssl, 8);
            if (rl == 0) atomicAdd(&ssacc[m], ssl);
        }
}

// ---------------------------------------------------------------------------
extern "C" void kernel_launch(void* const* d_in, const int* in_sizes, int n_in,
                              void* d_out, int out_size, void* d_ws, size_t ws_size,
                              hipStream_t stream) {
    const float* X = (const float*)d_in[0];
    const float* W1 = (const float*)d_in[1];
    const float* b1 = (const float*)d_in[2];
    const float* W2 = (const float*)d_in[3];
    const float* b2 = (const float*)d_in[4];
    float* out = (float*)d_out;
    char* ws = (char*)d_ws;

    constexpr size_t O_BufA    = 0;                                     // 33,554,432
    constexpr size_t O_BufB    = O_BufA + (size_t)N_ROWS * DIM * 2;     // 33,554,432
    constexpr size_t O_Pb      = O_BufB + (size_t)N_ROWS * DIM * 2;     //  2,097,152
    constexpr size_t O_PTb     = O_Pb + (size_t)N_ROWS * OUTD * 2;      //  2,097,152
    constexpr size_t O_Gb      = O_PTb + (size_t)OUTD * N_ROWS * 2;     //  2,097,152
    constexpr size_t O_PtXTb   = O_Gb + (size_t)DIM * DIM * 2;          //    131,072
    constexpr size_t O_ssB     = O_PtXTb + (size_t)DIM * OUTD * 2;      //     65,536
    constexpr size_t O_W1T     = O_ssB + (size_t)N_ROWS * 4;            //     32,768
    constexpr size_t O_ssA     = O_W1T + (size_t)HID * DIM * 2;         //     65,536
    constexpr size_t O_scratch = O_ssA + (size_t)N_ROWS * 4;            // = 73,695,232
    constexpr size_t WS_BIG = O_scratch + (size_t)16 * 589824 * 2;

    ushort* bufA  = (ushort*)(ws + O_BufA);
    ushort* bufB  = (ushort*)(ws + O_BufB);
    ushort* Pb    = (ushort*)(ws + O_Pb);
    ushort* PTb   = (ushort*)(ws + O_PTb);
    ushort* Gb    = (ushort*)(ws + O_Gb);
    ushort* PtXTb = (ushort*)(ws + O_PtXTb);
    float*  ssB   = (float*)(ws + O_ssB);
    ushort* W1T   = (ushort*)(ws + O_W1T);
    float*  ssA   = (float*)(ws + O_ssA);
    float*  z     = (float*)(ws + O_scratch);
    ushort* Gpart = (ushort*)(ws + O_scratch);
    ushort* PXpart = (ushort*)d_out;
    ushort* Gsum  = PTb;                       // PTb region reuse (dead)
    ushort* PXsum = PTb + 589824;
    (void)in_sizes; (void)n_in; (void)out_size;

    const bool big = ws_size >= WS_BIG;
    const int nzg = big ? 16 : 4;
    const int nzp = big ? 32 : 8;

    prep_w1t_k<<<64, 256, 0, stream>>>(W1, W1T);
    tobf16_k<<<N_ROWS, 256, 0, stream>>>(X, bufA, ssA);

    ushort* xm  = bufA;
    ushort* alt = bufB;
    float* ssCur = ssA;
    float* ssNxt = ssB;

    for (int it = 0; it < DEPTH; ++it) {
        if (big) {
            txz_k<<<4096 + 256, 256, 0, stream>>>(xm, ssCur, alt, W1T, b1, z);
        } else {
            transpose_k<<<dim3(N_ROWS / 64, DIM / 64), 256, 0, stream>>>(xm, ssCur, alt);
            zgemm_k<<<N_ROWS / 64, 256, 0, stream>>>(xm, W1T, b1, z, ssCur);
        }
        head_k<<<N_ROWS / 256, 256, 0, stream>>>(z, W2, b2, Pb, PTb, nullptr, 1);
        if (big) {
            gp_k<<<576 + 256, 256, 0, stream>>>(alt, PTb, Gpart, PXpart);
        } else {
            gemm_nt_k<128, 128, 1><<<dim3(36 * 4, 1, 1), 256, 0, stream>>>(
                alt, N_ROWS, alt, N_ROWS, 4096, Gpart, 36 * 16384, 4);
            gemm_nt_k<128, 64, 0><<<dim3(8, 1, 8), 256, 0, stream>>>(
                alt, N_ROWS, PTb, N_ROWS, 2048, PXpart, DIM * OUTD, 0);
        }
        reduce_k<<<320, 256, 0, stream>>>(Gpart, PXpart, Gsum, PXsum, nzg, nzp);
        castgp_k<<<1088, 256, 0, stream>>>(Gsum, PXsum, Gb, PtXTb, ssNxt);
        // X_{t+1} = Xn + g*(P@PtX - Xn@G); dedicated kernel
        upd1_k<<<dim3(N_ROWS / 128, DIM / 128, 1), 256, 0, stream>>>(
            xm, Gb, Pb, PtXTb, alt, ssCur, GAMMA, ssNxt);
        ushort* tmp = xm; xm = alt; alt = tmp;
        float* ts2 = ssCur; ssCur = ssNxt; ssNxt = ts2;
    }

    zgemm_k<<<N_ROWS / 64, 256, 0, stream>>>(xm, W1T, b1, z, nullptr);
    head_k<<<N_ROWS / 256, 256, 0, stream>>>(z, W2, b2, Pb, PTb, out, 0);
}

// Round 11
// 930.657 us; speedup vs baseline: 1.0385x; 1.0385x over previous
//
#include <hip/hip_runtime.h>

// CKAFormer R18 = exact R16 revert (proven best, 907.5us).
// R17 post-mortem: pair-access epilogue REGRESSED upd1 52->66.3us. Mechanism:
// EPI0's pairing wins by halving ATOMICS; here it replaced cheap 2B stores
// with dword stores while idling half the wave (rl&1 predication) through all
// 16 epilogue iterations and doubling per-even-lane VALU work behind a
// __shfl_xor dependency chain. MfmaUtil 28.8->22. Plain per-lane 2B epilogue
// (R16) is the right form — L2 absorbs the scattered stores.
// Session summary of proven structure (all measured):
// - zero-atomic split-K partial gemms + coalesced reduce + L2-resident
//   gather/cast (R8-R10), grid-fused glue txz/gp (R11),
//   lb(256,4) occupancy + tail quantization (R16: upd1 62.5->52us).
// - Tested & rejected: 8-phase 256^2 for this op (R12/R13 A/B: 2x slower,
//   1 blk/CU occupancy-bound), LDS-capture epilogue (R14 write storm),
//   dedicated-kernel regalloc isolation (R15 null), pair epilogue (R17).

#define N_ROWS 16384
#define DIM 1024
#define HID 16
#define OUTD 64
#define DEPTH 6
#define GAMMA 1e-4f

typedef short bf16x8 __attribute__((ext_vector_type(8)));
typedef unsigned short u16x8 __attribute__((ext_vector_type(8)));
typedef float f32x4 __attribute__((ext_vector_type(4)));

#define AS1C(p) ((const __attribute__((address_space(1))) void*)(p))
#define AS3(p)  ((__attribute__((address_space(3))) void*)(p))

__device__ __forceinline__ unsigned short f2bf(float f) {
    unsigned u = __builtin_bit_cast(unsigned, f);
    u += 0x7fffu + ((u >> 16) & 1u);   // round-to-nearest-even
    return (unsigned short)(u >> 16);
}
__device__ __forceinline__ float b2f(ushort u) {
    unsigned x = ((unsigned)u) << 16;
    return __builtin_bit_cast(float, x);
}
// stored offset of logical element n within a swizzled row keyed by (row&7)
__device__ __forceinline__ int swz(int n, int row) {
    return (n & ~63) | ((((n >> 3) & 7) ^ (row & 7)) << 3) | (n & 7);
}

// ---------------------------------------------------------------------------
// Once per launch: master Xm = bf16(X) swizzled rows + ssout[row] = ||X[row]||^2.
__global__ __launch_bounds__(256) void tobf16_k(const float* __restrict__ X,
        ushort* __restrict__ Xm, float* __restrict__ ssout) {
    int row = blockIdx.x, t = threadIdx.x;
    float4 v = ((const float4*)(X + (size_t)row * DIM))[t];
    ushort4 o4;
    o4.x = f2bf(v.x); o4.y = f2bf(v.y); o4.z = f2bf(v.z); o4.w = f2bf(v.w);
    *(ushort4*)(Xm + (size_t)row * DIM + swz(t * 4, row)) = o4;
    float ss = v.x * v.x + v.y * v.y + v.z * v.z + v.w * v.w;
    for (int o = 32; o > 0; o >>= 1) ss += __shfl_down(ss, o);
    __shared__ float wsum[4];
    if ((t & 63) == 0) wsum[t >> 6] = ss;
    __syncthreads();
    if (t == 0) ssout[row] = wsum[0] + wsum[1] + wsum[2] + wsum[3];
}

// ---------------------------------------------------------------------------
// XnT[d][k] = bf16(Xm[k][d] / ||X[k]||), swizzled by d. LDS 64x65 f32 tile.
__device__ __forceinline__ void transpose_body(const ushort* __restrict__ Xm,
        const float* __restrict__ ss, ushort* __restrict__ XnT,
        int bx, int by, float* ts, float* riS) {
    int r0 = bx * 64;   // source row (k) tile
    int c0 = by * 64;   // source col (d) tile
    int t = threadIdx.x;
    if (t < 64) riS[t] = 1.0f / sqrtf(ss[r0 + t]);
    __syncthreads();
#pragma unroll
    for (int i = 0; i < 2; ++i) {
        int idx = i * 256 + t;
        int r = idx >> 3, lg = idx & 7;
        int rr = r0 + r;
        const ushort* p = Xm + (size_t)rr * DIM + c0 + ((lg ^ (rr & 7)) << 3);
        u16x8 a = *(const u16x8*)p;
        float s = riS[r];
        float* d = &ts[r * 65 + lg * 8];
#pragma unroll
        for (int u = 0; u < 8; ++u) d[u] = b2f(a[u]) * s;
    }
    __syncthreads();
#pragma unroll
    for (int i = 0; i < 2; ++i) {
        int g = i * 256 + t;
        int c = g >> 3;
        int rg = g & 7;
        u16x8 pk;
#pragma unroll
        for (int u = 0; u < 8; ++u) pk[u] = f2bf(ts[(rg * 8 + u) * 65 + c]);
        *(u16x8*)(XnT + (size_t)(c0 + c) * N_ROWS + r0 + ((rg ^ (c & 7)) << 3)) = pk;
    }
}

// ---------------------------------------------------------------------------
// z[m][h] = (Xm[m]·W1[:,h]) / ||X[m]|| + b1[h]   (ss=nullptr -> no scale; final).
__device__ __forceinline__ void zgemm_body(const ushort* __restrict__ Xm,
        const ushort* __restrict__ W1T, const float* __restrict__ b1,
        float* __restrict__ z, const float* __restrict__ ss, int bidx) {
    int t = threadIdx.x;
    int wave = t >> 6, lane = t & 63;
    int rl = lane & 15, q = lane >> 4;
    int rowbase = bidx * 64 + wave * 16;
    int m = rowbase + rl;
    int msw = m & 7;
    const ushort* arow = Xm + (size_t)m * DIM;
    const ushort* brow = W1T + (size_t)rl * DIM + q * 8;
    f32x4 acc = {0.f, 0.f, 0.f, 0.f};
#pragma unroll 8
    for (int kt = 0; kt < DIM; kt += 32) {
        int gl = ((kt >> 3) & 7) | q;
        int off = (kt & ~63) + ((gl ^ msw) << 3);
        bf16x8 a = *(const bf16x8*)(arow + off);
        bf16x8 b = *(const bf16x8*)(brow + kt);
        acc = __builtin_amdgcn_mfma_f32_16x16x32_bf16(a, b, acc, 0, 0, 0);
    }
#pragma unroll
    for (int rg = 0; rg < 4; ++rg) {
        int mm = rowbase + q * 4 + rg;
        float s = ss ? 1.0f / sqrtf(ss[mm]) : 1.0f;
        z[(size_t)mm * HID + rl] = acc[rg] * s + b1[rl];
    }
}

// ---------------------------------------------------------------------------
// Fused transpose (blocks 0..4095) + zgemm (blocks 4096..4351).
__global__ __launch_bounds__(256) void txz_k(const ushort* __restrict__ Xm,
        const float* __restrict__ ss, ushort* __restrict__ XnT,
        const ushort* __restrict__ W1T, const float* __restrict__ b1,
        float* __restrict__ z) {
    __shared__ float ts[64 * 65];
    __shared__ float riS[64];
    int bid = blockIdx.x;
    if (bid < 4096) transpose_body(Xm, ss, XnT, bid & 255, bid >> 8, ts, riS);
    else            zgemm_body(Xm, W1T, b1, z, ss, bid - 4096);
}

// standalone wrappers (small path / final)
__global__ __launch_bounds__(256) void transpose_k(const ushort* __restrict__ Xm,
        const float* __restrict__ ss, ushort* __restrict__ XnT) {
    __shared__ float ts[64 * 65];
    __shared__ float riS[64];
    transpose_body(Xm, ss, XnT, blockIdx.x, blockIdx.y, ts, riS);
}
__global__ __launch_bounds__(256) void zgemm_k(const ushort* __restrict__ Xm,
        const ushort* __restrict__ W1T, const float* __restrict__ b1,
        float* __restrict__ z, const float* __restrict__ ss) {
    zgemm_body(Xm, W1T, b1, z, ss, blockIdx.x);
}

// ---------------------------------------------------------------------------
__global__ __launch_bounds__(256) void prep_w1t_k(const float* __restrict__ W1,
        ushort* __restrict__ W1T) {
    int idx = blockIdx.x * 256 + threadIdx.x;   // 16384
    int h = idx >> 10, j = idx & 1023;
    W1T[idx] = f2bf(W1[j * HID + h]);
}

// ---------------------------------------------------------------------------
// Per row: h = relu(z); logits = h@W2 + b2; softmax -> Pb (swizzled by m&7)
// + PTb (rows o, swizzled by o&7), or (do_softmax=0) logits f32 to out.
__global__ __launch_bounds__(256) void head_k(const float* __restrict__ z,
        const float* __restrict__ W2, const float* __restrict__ b2,
        ushort* __restrict__ Pb, ushort* __restrict__ PTb,
        float* __restrict__ out, int do_softmax) {
    __shared__ float w2s[HID * OUTD];
    __shared__ float b2s[OUTD];
    int t = threadIdx.x;
    ((float4*)w2s)[t] = ((const float4*)W2)[t];
    if (t < OUTD) b2s[t] = b2[t];
    __syncthreads();
    int m = blockIdx.x * 256 + t;
    float h[HID];
    const float4* zp = (const float4*)(z + (size_t)m * HID);
#pragma unroll
    for (int i = 0; i < 4; ++i) {
        float4 v = zp[i];
        h[i * 4 + 0] = fmaxf(v.x, 0.f); h[i * 4 + 1] = fmaxf(v.y, 0.f);
        h[i * 4 + 2] = fmaxf(v.z, 0.f); h[i * 4 + 3] = fmaxf(v.w, 0.f);
    }
    float lo[OUTD];
#pragma unroll
    for (int o = 0; o < OUTD; ++o) lo[o] = b2s[o];
    for (int i = 0; i < HID; ++i) {
        float hv = h[i];
#pragma unroll
        for (int o = 0; o < OUTD; ++o) lo[o] += hv * w2s[i * OUTD + o];
    }
    if (do_softmax) {
        float mx = lo[0];
#pragma unroll
        for (int o = 1; o < OUTD; ++o) mx = fmaxf(mx, lo[o]);
        float sm = 0.f;
#pragma unroll
        for (int o = 0; o < OUTD; ++o) { float e = __expf(lo[o] - mx); lo[o] = e; sm += e; }
        float inv = 1.0f / sm;
#pragma unroll
        for (int o8 = 0; o8 < 8; ++o8) {
            u16x8 pk;
#pragma unroll
            for (int u = 0; u < 8; ++u) pk[u] = f2bf(lo[o8 * 8 + u] * inv);
            ((u16x8*)(Pb + (size_t)m * OUTD))[o8 ^ (m & 7)] = pk;
        }
#pragma unroll
        for (int o = 0; o < OUTD; ++o)
            PTb[(size_t)o * N_ROWS + swz(m, o)] = f2bf(lo[o] * inv);
    } else {
        float4* op = (float4*)(out + (size_t)m * OUTD);
#pragma unroll
        for (int o4 = 0; o4 < 16; ++o4) {
            float4 v; v.x = lo[o4 * 4 + 0]; v.y = lo[o4 * 4 + 1];
            v.z = lo[o4 * 4 + 2]; v.w = lo[o4 * 4 + 3];
            op[o4] = v;
        }
    }
}

// ---------------------------------------------------------------------------
// Pass A: coalesced split-K reduction -> compact bf16 sums.
__global__ __launch_bounds__(256) void reduce_k(const ushort* __restrict__ Gp,
        const ushort* __restrict__ PXp, ushort* __restrict__ Gsum,
        ushort* __restrict__ PXsum, int nzg, int nzp) {
    int idx = blockIdx.x * 256 + threadIdx.x;   // 81920 units of 8 elems
    if (idx < 73728) {
        size_t off = (size_t)idx * 8;
        float acc[8] = {0.f, 0.f, 0.f, 0.f, 0.f, 0.f, 0.f, 0.f};
        for (int zz = 0; zz < nzg; ++zz) {
            u16x8 v = *(const u16x8*)(Gp + (size_t)zz * 589824 + off);
#pragma unroll
            for (int u = 0; u < 8; ++u) acc[u] += b2f(v[u]);
        }
        u16x8 o;
#pragma unroll
        for (int u = 0; u < 8; ++u) o[u] = f2bf(acc[u]);
        *(u16x8*)(Gsum + off) = o;
    } else {
        size_t off = (size_t)(idx - 73728) * 8;
        float acc[8] = {0.f, 0.f, 0.f, 0.f, 0.f, 0.f, 0.f, 0.f};
        for (int zz = 0; zz < nzp; ++zz) {
            u16x8 v = *(const u16x8*)(PXp + (size_t)zz * 65536 + off);
#pragma unroll
            for (int u = 0; u < 8; ++u) acc[u] += b2f(v[u]);
        }
        u16x8 o;
#pragma unroll
        for (int u = 0; u < 8; ++u) o[u] = f2bf(acc[u]);
        *(u16x8*)(PXsum + off) = o;
    }
}

// ---------------------------------------------------------------------------
// Pass B: gather/mirror/swizzle of the L2-resident sums + zero next ssacc.
__global__ __launch_bounds__(256) void castgp_k(const ushort* __restrict__ Gsum,
        const ushort* __restrict__ PXsum, ushort* __restrict__ Gb,
        ushort* __restrict__ PtXTb, float* __restrict__ ssz) {
    if (blockIdx.x < 64) ssz[blockIdx.x * 256 + threadIdx.x] = 0.f;
    int idx = blockIdx.x * 256 + threadIdx.x;   // 278528 units
    if (idx < 262144) {
        int n = idx >> 8;
        int so = (idx & 255) * 4;
        int k0 = (so & ~63) | ((((so >> 3) & 7) ^ (n & 7)) << 3) | (so & 7);
        ushort po[4];
#pragma unroll
        for (int u = 0; u < 4; ++u) {
            int kk = k0 + u;
            int a = min(n, kk), b = max(n, kk);
            int tm = a >> 7, tn = b >> 7;
            int tlin = tm * 8 - ((tm * (tm - 1)) >> 1) + (tn - tm);
            size_t off = (size_t)tlin * 16384 + (size_t)(a & 127) * 128 + (b & 127);
            po[u] = (ushort)(Gsum[off] ^ 0x8000u);   // negate via sign bit
        }
        ushort4 o; o.x = po[0]; o.y = po[1]; o.z = po[2]; o.w = po[3];
        *(ushort4*)(Gb + (size_t)n * DIM + so) = o;
    } else {
        int vv = idx - 262144;                  // 16384 units
        int d = vv >> 4;
        int so = (vv & 15) * 4;
        int k0 = ((((so >> 3) & 7) ^ (d & 7)) << 3) | (so & 7);
        const ushort* src = PXsum + (size_t)d * OUTD + k0;
        ushort4 o; o.x = src[0]; o.y = src[1]; o.z = src[2]; o.w = src[3];
        *(ushort4*)(PtXTb + (size_t)d * OUTD + so) = o;
    }
}

// ---------------------------------------------------------------------------
// Partial-store NT MFMA GEMM body (R5-proven loop; EPI0 only).
template<int BM, int BN, int TRI>
__device__ __forceinline__ void gemm0_body(
        const ushort* __restrict__ A0, int lda0,
        const ushort* __restrict__ B0, int ldb0, int k0len,
        ushort* __restrict__ C, int pstride, int nz,
        int bx, int by, int bz, ushort* ls) {
    constexpr int WTN = BN / 2;
    constexpr int NF = WTN / 16;
    constexpr int NAW = BM / 64;     // waves staging A
    constexpr int NBW = BN / 64;     // waves staging B
    ushort* lsA = ls;
    ushort* lsB = ls + BM * 64;
    int t = threadIdx.x;
    int wave = t >> 6, lane = t & 63;
    int rl = lane & 15, q = lane >> 4;
    int wm = wave & 1, wn = wave >> 1;
    int m0, n0, zidx, tlin = 0;
    if (TRI) {
        int bid = bx;
        int bxx, tm = 0;
        if (nz == 16) {                 // R7-proven mapping: grid 8*36*2
            int rest = bid >> 3;
            bxx = rest % 36;
            int zhi = rest / 36;
            zidx = (bid & 7) | (zhi << 3);
        } else {                        // fallback: grid 36*4
            zidx = bid & 3;
            bxx = bid >> 2;
        }
        tlin = bxx;
        while (bxx >= 8 - tm) { bxx -= 8 - tm; ++tm; }
        m0 = tm * 128; n0 = (tm + bxx) * 128;
    } else {
        m0 = bx * BM; n0 = by * BN; zidx = bz;
    }
    int lrow8 = lane >> 3, lgrp = lane & 7;
    bool isA = wave < NAW;
    bool active = wave < NAW + NBW;
    int wlocal = isA ? wave : wave - NAW;
    ushort* dstb = ls + (isA ? 0 : BM * 64) + wlocal * 4096;

    f32x4 acc[4][NF];
#pragma unroll
    for (int i = 0; i < 4; ++i)
#pragma unroll
        for (int j = 0; j < NF; ++j) acc[i][j] = f32x4{0.f, 0.f, 0.f, 0.f};

    const ushort* srcb;
    size_t ldS;
    if (isA) {
        srcb = A0 + (size_t)(m0 + wlocal * 64 + lrow8) * lda0 + lgrp * 8;
        ldS = (size_t)lda0;
    } else {
        srcb = B0 + (size_t)(n0 + wlocal * 64 + lrow8) * ldb0 + lgrp * 8;
        ldS = (size_t)ldb0;
    }
    srcb += zidx * k0len;
    for (int kt = 0; kt < k0len; kt += 64) {
        if (active) {
#pragma unroll
            for (int c = 0; c < 8; ++c)
                __builtin_amdgcn_global_load_lds(AS1C(srcb + c * 8 * ldS),
                                                 AS3(dstb + c * 512), 16, 0, 0);
            srcb += 64;
        }
        __syncthreads();
#pragma unroll
        for (int s = 0; s < 2; ++s) {
            bf16x8 af[4], bfr[NF];
#pragma unroll
            for (int i = 0; i < 4; ++i) {
                int row = wm * 64 + i * 16 + rl;
                int sg = ((s << 2) | q) ^ (row & 7);
                af[i] = *(const bf16x8*)&lsA[row * 64 + sg * 8];
            }
#pragma unroll
            for (int j = 0; j < NF; ++j) {
                int row = wn * WTN + j * 16 + rl;
                int sg = ((s << 2) | q) ^ (row & 7);
                bfr[j] = *(const bf16x8*)&lsB[row * 64 + sg * 8];
            }
#pragma unroll
            for (int i = 0; i < 4; ++i)
#pragma unroll
                for (int j = 0; j < NF; ++j)
                    acc[i][j] = __builtin_amdgcn_mfma_f32_16x16x32_bf16(
                        af[i], bfr[j], acc[i][j], 0, 0, 0);
        }
        __syncthreads();
    }

    // plain bf16 pair stores into this z-slice's partial buffer
    ushort* Cb = C + (size_t)zidx * (size_t)pstride;
#pragma unroll
    for (int i = 0; i < 4; ++i)
#pragma unroll
        for (int j = 0; j < NF; ++j)
#pragma unroll
            for (int rg = 0; rg < 4; ++rg) {
                float v = acc[i][j][rg];
                float vp = __shfl_xor(v, 1);   // partner lane's (n^1) value
                if ((rl & 1) == 0) {
                    int ml = wm * 64 + i * 16 + q * 4 + rg;
                    int nl = wn * WTN + j * 16 + rl;
                    size_t off;
                    if (TRI)
                        off = (size_t)tlin * (BM * BN) + (size_t)ml * BN + nl;
                    else
                        off = (size_t)(m0 + ml) * 0 + (size_t)(m0 + ml) * OUTD + nl; // non-TRI: ldc=OUTD
                    unsigned pk = (unsigned)f2bf(v) | ((unsigned)f2bf(vp) << 16);
                    *(unsigned*)(Cb + off) = pk;
                }
            }
}

template<int BM, int BN, int TRI>
__global__ __launch_bounds__(256, 4) void gemm_nt_k(
        const ushort* __restrict__ A0, int lda0,
        const ushort* __restrict__ B0, int ldb0, int k0len,
        ushort* __restrict__ C, int pstride, int nz) {
    __shared__ ushort ls[(BM + BN) * 64];
    gemm0_body<BM, BN, TRI>(A0, lda0, B0, ldb0, k0len, C, pstride, nz,
        blockIdx.x, blockIdx.y, blockIdx.z, ls);
}

// ---------------------------------------------------------------------------
// Fused G-gemm (blocks 0..575, TRI split-K 16) + PtX-gemm (576..831, split-K 32).
__global__ __launch_bounds__(256, 4) void gp_k(const ushort* __restrict__ XnT,
        const ushort* __restrict__ PTb, ushort* __restrict__ Gpart,
        ushort* __restrict__ PXpart) {
    __shared__ ushort ls[256 * 64];
    int bid = blockIdx.x;
    if (bid < 576) {
        gemm0_body<128, 128, 1>(XnT, N_ROWS, XnT, N_ROWS, 1024,
            Gpart, 36 * 16384, 16, bid, 0, 0, ls);
    } else {
        int b2 = bid - 576;
        gemm0_body<128, 64, 0>(XnT, N_ROWS, PTb, N_ROWS, 512,
            PXpart, DIM * OUTD, 0, b2 & 7, 0, b2 >> 3, ls);
    }
}

// ---------------------------------------------------------------------------
// Dedicated update gemm: X_{t+1} = Xn + g*(P@PtX - Xn@G).
// seg0: Xm(ld DIM) @ Gb(ld DIM)^T, K=1024. rvv scale. seg1: Pb @ PtXTb
// (ld OUTD), K=64. Epilogue: per-lane 2B scattered base-load + store (R16
// form — proven fastest; pairing regressed, LDS-capture regressed).
__global__ __launch_bounds__(256, 4) void upd1_k(
        const ushort* __restrict__ Xm, const ushort* __restrict__ Gb,
        const ushort* __restrict__ Pb, const ushort* __restrict__ PtXTb,
        ushort* __restrict__ Cm, const float* __restrict__ ssrd,
        float gamma, float* __restrict__ ssacc) {
    __shared__ ushort ls[256 * 64];
    ushort* lsA = ls;
    ushort* lsB = ls + 128 * 64;
    int t = threadIdx.x;
    int wave = t >> 6, lane = t & 63;
    int rl = lane & 15, q = lane >> 4;
    int wm = wave & 1, wn = wave >> 1;
    int m0 = blockIdx.x * 128, n0 = blockIdx.y * 128;
    int lrow8 = lane >> 3, lgrp = lane & 7;
    bool isA = wave < 2;
    int wlocal = isA ? wave : wave - 2;
    ushort* dstb = ls + (isA ? 0 : 8192) + wlocal * 4096;

    f32x4 acc[4][4];
#pragma unroll
    for (int i = 0; i < 4; ++i)
#pragma unroll
        for (int j = 0; j < 4; ++j) acc[i][j] = f32x4{0.f, 0.f, 0.f, 0.f};

    // seg0: K=1024
    {
        const ushort* srcb = isA
            ? Xm + (size_t)(m0 + wlocal * 64 + lrow8) * DIM + lgrp * 8
            : Gb + (size_t)(n0 + wlocal * 64 + lrow8) * DIM + lgrp * 8;
        for (int kt = 0; kt < 1024; kt += 64) {
#pragma unroll
            for (int c = 0; c < 8; ++c)
                __builtin_amdgcn_global_load_lds(AS1C(srcb + c * 8 * DIM),
                                                 AS3(dstb + c * 512), 16, 0, 0);
            srcb += 64;
            __syncthreads();
#pragma unroll
            for (int s = 0; s < 2; ++s) {
                bf16x8 af[4], bfr[4];
#pragma unroll
                for (int i = 0; i < 4; ++i) {
                    int row = wm * 64 + i * 16 + rl;
                    int sg = ((s << 2) | q) ^ (row & 7);
                    af[i] = *(const bf16x8*)&lsA[row * 64 + sg * 8];
                }
#pragma unroll
                for (int j = 0; j < 4; ++j) {
                    int row = wn * 64 + j * 16 + rl;
                    int sg = ((s << 2) | q) ^ (row & 7);
                    bfr[j] = *(const bf16x8*)&lsB[row * 64 + sg * 8];
                }
#pragma unroll
                for (int i = 0; i < 4; ++i)
#pragma unroll
                    for (int j = 0; j < 4; ++j)
                        acc[i][j] = __builtin_amdgcn_mfma_f32_16x16x32_bf16(
                            af[i], bfr[j], acc[i][j], 0, 0, 0);
            }
            __syncthreads();
        }
    }

    // rvv scale (Xn@G needs rinv[m])
    float rvv[4][4];
#pragma unroll
    for (int i = 0; i < 4; ++i)
#pragma unroll
        for (int rg = 0; rg < 4; ++rg) {
            rvv[i][rg] = 1.0f / sqrtf(ssrd[m0 + wm * 64 + i * 16 + q * 4 + rg]);
#pragma unroll
            for (int j = 0; j < 4; ++j) acc[i][j][rg] *= rvv[i][rg];
        }

    // seg1: K=64
    {
        const ushort* srcb = isA
            ? Pb + (size_t)(m0 + wlocal * 64 + lrow8) * OUTD + lgrp * 8
            : PtXTb + (size_t)(n0 + wlocal * 64 + lrow8) * OUTD + lgrp * 8;
#pragma unroll
        for (int c = 0; c < 8; ++c)
            __builtin_amdgcn_global_load_lds(AS1C(srcb + c * 8 * OUTD),
                                             AS3(dstb + c * 512), 16, 0, 0);
        __syncthreads();
#pragma unroll
        for (int s = 0; s < 2; ++s) {
            bf16x8 af[4], bfr[4];
#pragma unroll
            for (int i = 0; i < 4; ++i) {
                int row = wm * 64 + i * 16 + rl;
                int sg = ((s << 2) | q) ^ (row & 7);
                af[i] = *(const bf16x8*)&lsA[row * 64 + sg * 8];
            }
#pragma unroll
            for (int j = 0; j < 4; ++j) {
                int row = wn * 64 + j * 16 + rl;
                int sg = ((s << 2) | q) ^ (row & 7);
                bfr[j] = *(const bf16x8*)&lsB[row * 64 + sg * 8];
            }
#pragma unroll
            for (int i = 0; i < 4; ++i)
#pragma unroll
                for (int j = 0; j < 4; ++j)
                    acc[i][j] = __builtin_amdgcn_mfma_f32_16x16x32_bf16(
                        af[i], bfr[j], acc[i][j], 0, 0, 0);
        }
    }

    // epilogue: vf = base*rinv + gamma*acc; bf16 master write + ss atomics.
#pragma unroll
    for (int i = 0; i < 4; ++i)
#pragma unroll
        for (int rg = 0; rg < 4; ++rg) {
            int m = m0 + wm * 64 + i * 16 + q * 4 + rg;
            float ssl = 0.f;
#pragma unroll
            for (int j = 0; j < 4; ++j) {
                int n = n0 + wn * 64 + j * 16 + rl;
                int so = swz(n, m);
                float base = b2f(Xm[(size_t)m * DIM + so]);
                float vf = base * rvv[i][rg] + gamma * acc[i][j][rg];
                Cm[(size_t)m * DIM + so] = f2bf(vf);
                ssl += vf * vf;
            }
            ssl += __shfl_xor(ssl, 1);
            ssl += __shfl_xor(ssl, 2);
            ssl += __shfl_xor(ssl, 4);
            ssl += __shfl_xor(ssl, 8);
            if (rl == 0) atomicAdd(&ssacc[m], ssl);
        }
}

// ---------------------------------------------------------------------------
extern "C" void kernel_launch(void* const* d_in, const int* in_sizes, int n_in,
                              void* d_out, int out_size, void* d_ws, size_t ws_size,
                              hipStream_t stream) {
    const float* X = (const float*)d_in[0];
    const float* W1 = (const float*)d_in[1];
    const float* b1 = (const float*)d_in[2];
    const float* W2 = (const float*)d_in[3];
    const float* b2 = (const float*)d_in[4];
    float* out = (float*)d_out;
    char* ws = (char*)d_ws;

    constexpr size_t O_BufA    = 0;                                     // 33,554,432
    constexpr size_t O_BufB    = O_BufA + (size_t)N_ROWS * DIM * 2;     // 33,554,432
    constexpr size_t O_Pb      = O_BufB + (size_t)N_ROWS * DIM * 2;     //  2,097,152
    constexpr size_t O_PTb     = O_Pb + (size_t)N_ROWS * OUTD * 2;      //  2,097,152
    constexpr size_t O_Gb      = O_PTb + (size_t)OUTD * N_ROWS * 2;     //  2,097,152
    constexpr size_t O_PtXTb   = O_Gb + (size_t)DIM * DIM * 2;          //    131,072
    constexpr size_t O_ssB     = O_PtXTb + (size_t)DIM * OUTD * 2;      //     65,536
    constexpr size_t O_W1T     = O_ssB + (size_t)N_ROWS * 4;            //     32,768
    constexpr size_t O_ssA     = O_W1T + (size_t)HID * DIM * 2;         //     65,536
    constexpr size_t O_scratch = O_ssA + (size_t)N_ROWS * 4;            // = 73,695,232
    constexpr size_t WS_BIG = O_scratch + (size_t)16 * 589824 * 2;

    ushort* bufA  = (ushort*)(ws + O_BufA);
    ushort* bufB  = (ushort*)(ws + O_BufB);
    ushort* Pb    = (ushort*)(ws + O_Pb);
    ushort* PTb   = (ushort*)(ws + O_PTb);
    ushort* Gb    = (ushort*)(ws + O_Gb);
    ushort* PtXTb = (ushort*)(ws + O_PtXTb);
    float*  ssB   = (float*)(ws + O_ssB);
    ushort* W1T   = (ushort*)(ws + O_W1T);
    float*  ssA   = (float*)(ws + O_ssA);
    float*  z     = (float*)(ws + O_scratch);
    ushort* Gpart = (ushort*)(ws + O_scratch);
    ushort* PXpart = (ushort*)d_out;
    ushort* Gsum  = PTb;                       // PTb region reuse (dead)
    ushort* PXsum = PTb + 589824;
    (void)in_sizes; (void)n_in; (void)out_size;

    const bool big = ws_size >= WS_BIG;
    const int nzg = big ? 16 : 4;
    const int nzp = big ? 32 : 8;

    prep_w1t_k<<<64, 256, 0, stream>>>(W1, W1T);
    tobf16_k<<<N_ROWS, 256, 0, stream>>>(X, bufA, ssA);

    ushort* xm  = bufA;
    ushort* alt = bufB;
    float* ssCur = ssA;
    float* ssNxt = ssB;

    for (int it = 0; it < DEPTH; ++it) {
        if (big) {
            txz_k<<<4096 + 256, 256, 0, stream>>>(xm, ssCur, alt, W1T, b1, z);
        } else {
            transpose_k<<<dim3(N_ROWS / 64, DIM / 64), 256, 0, stream>>>(xm, ssCur, alt);
            zgemm_k<<<N_ROWS / 64, 256, 0, stream>>>(xm, W1T, b1, z, ssCur);
        }
        head_k<<<N_ROWS / 256, 256, 0, stream>>>(z, W2, b2, Pb, PTb, nullptr, 1);
        if (big) {
            gp_k<<<576 + 256, 256, 0, stream>>>(alt, PTb, Gpart, PXpart);
        } else {
            gemm_nt_k<128, 128, 1><<<dim3(36 * 4, 1, 1), 256, 0, stream>>>(
                alt, N_ROWS, alt, N_ROWS, 4096, Gpart, 36 * 16384, 4);
            gemm_nt_k<128, 64, 0><<<dim3(8, 1, 8), 256, 0, stream>>>(
                alt, N_ROWS, PTb, N_ROWS, 2048, PXpart, DIM * OUTD, 0);
        }
        reduce_k<<<320, 256, 0, stream>>>(Gpart, PXpart, Gsum, PXsum, nzg, nzp);
        castgp_k<<<1088, 256, 0, stream>>>(Gsum, PXsum, Gb, PtXTb, ssNxt);
        // X_{t+1} = Xn + g*(P@PtX - Xn@G); dedicated kernel
        upd1_k<<<dim3(N_ROWS / 128, DIM / 128, 1), 256, 0, stream>>>(
            xm, Gb, Pb, PtXTb, alt, ssCur, GAMMA, ssNxt);
        ushort* tmp = xm; xm = alt; alt = tmp;
        float* ts2 = ssCur; ssCur = ssNxt; ssNxt = ts2;
    }

    zgemm_k<<<N_ROWS / 64, 256, 0, stream>>>(xm, W1T, b1, z, nullptr);
    head_k<<<N_ROWS / 256, 256, 0, stream>>>(z, W2, b2, Pb, PTb, out, 0);
}